// Round 2
// baseline (244.388 us; speedup 1.0000x reference)
//
#include <hip/hip_runtime.h>

#define B_   64
#define T_   1024
#define C_   256
#define NEGF (-4294967295.0f)   // float(-2**32+1) == -2^32, matches reference fp32 cast
#define LN_EPS 1e-9f

typedef short  short8 __attribute__((ext_vector_type(8)));
typedef float  f32x16 __attribute__((ext_vector_type(16)));

union S8 { short8 v; unsigned int w[4]; };

// float -> bf16 (RNE), packed pair
__device__ __forceinline__ unsigned int pk2(float x, float y) {
  unsigned a = __float_as_uint(x); a = (a + 0x7fffu + ((a >> 16) & 1u)) >> 16;
  unsigned b = __float_as_uint(y); b = (b + 0x7fffu + ((b >> 16) & 1u)) >> 16;
  return a | (b << 16);
}

// async global->LDS, 16 B per lane
__device__ __forceinline__ void async16(const void* g, void* l) {
  __builtin_amdgcn_global_load_lds(
      (const __attribute__((address_space(1))) void*)g,
      (__attribute__((address_space(3))) void*)l,
      16, 0, 0);
}

// v += dpp-permuted(v); ctrl must be a literal
#define DPPADD(v, ctrl) \
  ((v) + __int_as_float(__builtin_amdgcn_update_dpp( \
      0, __float_as_int(v), (ctrl), 0xF, 0xF, true)))

// ---------------- small kernels ----------------

__global__ void detect_kernel(const unsigned int* __restrict__ mw,
                              int* __restrict__ flag) {
  int idx = blockIdx.x * 256 + threadIdx.x;   // 16384 words, safe for u8 or i32 buffer
  if (mw[idx] > 1u) atomicOr(flag, 1);
}

// one 64-bit key-mask word per (batch, 64-key tile)
__global__ void mask64_kernel(const unsigned int* __restrict__ mw,
                              const int* __restrict__ flag,
                              unsigned long long* __restrict__ mk) {
  int wid  = (blockIdx.x * 256 + threadIdx.x) >> 6;   // 0..1023
  int lane = threadIdx.x & 63;
  int g = wid * 64 + lane;                            // b*1024 + t
  int f = *flag;
  unsigned int wv = mw[f ? (g >> 2) : g];
  unsigned int v  = f ? ((wv >> ((g & 3) * 8)) & 0xffu) : wv;
  unsigned long long bal = __ballot(v != 0);
  if (lane == 0) mk[wid] = bal;
}

__global__ void finalize_kernel(const float* __restrict__ accum,
                                float* __restrict__ out) {
  int idx = blockIdx.x * 256 + threadIdx.x;   // B*C = 16384
  out[idx] = accum[idx] * (1.0f / T_);
}

// ---------------- pre-pass: bf16 K image + V^T image + colsum ----------------
// One block per (b, 32-row tile); x read exactly once via LDS staging.
// K image: row-major [row][256], 16B slot ck stored at ck ^ (row&31).
// V^T image: [b][tile16][c][64 keys], 16B slot j (8 keys) stored at j ^ (c&7).
__global__ __launch_bounds__(256) void convert_kv(const float* __restrict__ x,
                                                  short* __restrict__ xk,
                                                  short* __restrict__ xv,
                                                  float* __restrict__ colsum) {
  __shared__ float Xt[32 * 256];     // 32 KB fp32 tile [j][c]
  __shared__ float csum[4][256];     // 4 KB colsum partials
  const int blk = blockIdx.x, b = blk >> 5, tt = blk & 31;
  const int tid = threadIdx.x;
  const float* xt = x + (size_t)(b * 1024 + tt * 32) * 256;

  // phase 1: coalesced row reads -> LDS fp32 + swizzled bf16 K-image
#pragma unroll
  for (int u = 0; u < 4; ++u) {
    int id = u * 256 + tid;            // 1024 items: 32 rows x 32 chunks
    int row = id >> 5, ck = id & 31;
    const float* src = xt + row * 256 + ck * 8;
    float4 a  = *(const float4*)src;
    float4 c4 = *(const float4*)(src + 4);
    *(float4*)&Xt[row * 256 + ck * 8]     = a;
    *(float4*)&Xt[row * 256 + ck * 8 + 4] = c4;
    S8 s; s.w[0] = pk2(a.x, a.y);  s.w[1] = pk2(a.z, a.w);
          s.w[2] = pk2(c4.x, c4.y); s.w[3] = pk2(c4.z, c4.w);
    *(short8*)(xk + (size_t)(b * 1024 + tt * 32 + row) * 256 + ((ck ^ row) << 3)) = s.v;
  }
  __syncthreads();

  // phase 2: transpose from LDS -> swizzled V^T image + colsum partials
  const int ck = tid >> 6, clo = tid & 63;
  short* vout = xv + (size_t)(b * 16 + (tt >> 1)) * 16384;
  const int jj = (tt & 1) * 4 + ck;      // 8-key block within 64-key tile
#pragma unroll
  for (int g = 0; g < 4; ++g) {
    int c = g * 64 + clo;
    float vs[8]; float s = 0.f;
#pragma unroll
    for (int e = 0; e < 8; ++e) { vs[e] = Xt[(ck * 8 + e) * 256 + c]; s += vs[e]; }
    S8 o;
    o.w[0] = pk2(vs[0], vs[1]); o.w[1] = pk2(vs[2], vs[3]);
    o.w[2] = pk2(vs[4], vs[5]); o.w[3] = pk2(vs[6], vs[7]);
    *(short8*)(vout + (size_t)c * 64 + ((jj ^ (c & 7)) << 3)) = o.v;
    csum[ck][c] = s;
  }
  __syncthreads();
  if (tid < 256) {
    float s = csum[0][tid] + csum[1][tid] + csum[2][tid] + csum[3][tid];
    atomicAdd(&colsum[b * 256 + tid], s);
  }
}

// ---------------- flash kernel (32x32x16 MFMA, 32 q-rows/wave) ----------------
// 256 blocks x 512 threads, 1 block/CU, 128 KB LDS.
// Block = (batch b, q-tile pair (t, 7-t)) processed CONCURRENTLY:
// waves 0-3 own q-tile t, waves 4-7 own q-tile 7-t; each wave owns 32 q rows
// for the whole kernel (no mid-loop finalize). One ascending stream of
// nt = 16-2t 64-key tiles; per-wave causal skip. Scores as S^T (D cols = q)
// and output as O^T = V^T P^T (D cols = q) so softmax stats/rescale are
// lane-local. Double-buffered async DMA, one barrier per tile.
__global__ __launch_bounds__(512, 2) void flash6(
    const short* __restrict__ xk,
    const short* __restrict__ xv,
    const unsigned long long* __restrict__ mk,
    const float* __restrict__ gamma,
    const float* __restrict__ beta,
    const float* __restrict__ colsum,
    float* __restrict__ accum)
{
  __shared__ __align__(16) short KsD[2][64 * 256];   // 2 x 32 KB  K rows
  __shared__ __align__(16) short VtD[2][256 * 64];   // 2 x 32 KB  V^T [c][64k]

  const int i0 = blockIdx.x;
  const int x8 = i0 & 7;            // XCD id (heuristic: round-robin dispatch)
  const int s  = i0 >> 3;           // 0..31
  const int b  = x8 + 8 * (s & 7);  // batches = x8 (mod 8) cluster on XCD x8
  const int t  = s >> 3;            // 0..3 -> q-tile pair (t, 7-t)

  const int tid  = threadIdx.x;
  const int w    = tid >> 6;        // 0..7
  const int lane = tid & 63;
  const int h    = lane >> 5;       // lane half
  const int q5   = lane & 31;

  const int qt   = (w < 4) ? t : (7 - t);
  const int n0   = qt * 128 + (w & 3) * 32;
  const int qrow = n0 + q5;
  const int nt   = 16 - 2 * t;            // key tiles for this block
  const int last_act = (n0 + 31) >> 6;    // wave's last causally-active tile

  // Q fragments: B-operand, lane holds Q[q = n0+q5][ks*16 + 8h + e]
  short8 qf[16];
  {
    const short* qp = xk + (size_t)(b * 1024 + qrow) * 256;
#pragma unroll
    for (int ks = 0; ks < 16; ++ks)
      qf[ks] = *(const short8*)(qp + (((ks * 2 + h) ^ q5) << 3));
  }

  f32x16 Oa[8];                     // O^T accum: row c = cb*32+(reg&3)+8*(reg>>2)+4h, col q
#pragma unroll
  for (int cb = 0; cb < 8; ++cb)
#pragma unroll
    for (int e = 0; e < 16; ++e) Oa[cb][e] = 0.f;

  // prefetch tile 0 into buf 0 (32 KB K + 32 KB V, linear DMA)
  {
    const short* gk = xk + (size_t)b * 1024 * 256;
    const short* gv = xv + (size_t)b * 16 * 16384;
#pragma unroll
    for (int u = 0; u < 4; ++u) {
      const int seg = w * 4 + u;    // 0..31, 1 KB each
      async16(gk + seg * 512 + lane * 8, &KsD[0][seg * 512]);
      async16(gv + seg * 512 + lane * 8, &VtD[0][seg * 512]);
    }
  }

  float m = NEGF, l = 0.f;
  __syncthreads();

  for (int kt = 0; kt < nt; ++kt) {
    const int ibuf = kt & 1;
    if (kt + 1 < nt) {              // async prefetch next tile into other buffer
      const short* gk = xk + (size_t)(b * 1024 + (kt + 1) * 64) * 256;
      const short* gv = xv + (size_t)(b * 16 + kt + 1) * 16384;
#pragma unroll
      for (int u = 0; u < 4; ++u) {
        const int seg = w * 4 + u;
        async16(gk + seg * 512 + lane * 8, &KsD[1 - ibuf][seg * 512]);
        async16(gv + seg * 512 + lane * 8, &VtD[1 - ibuf][seg * 512]);
      }
    }

    if (kt <= last_act) {           // wave-uniform causal tile skip
      const int ktb = kt * 64;
      const unsigned long long mwt = mk[b * 16 + kt];

      // ---- scores S^T = K·Q^T: two 32-key halves, two independent MFMA chains
      f32x16 acc0, acc1;            // acc0: keys ktb+{(j&3)+8*(j>>2)+4h}; acc1: +32
      {
#pragma unroll
        for (int e = 0; e < 16; ++e) { acc0[e] = 0.f; acc1[e] = 0.f; }
        const short* kr0 = &KsD[ibuf][q5 * 256];
        const short* kr1 = &KsD[ibuf][(32 + q5) * 256];
#pragma unroll
        for (int ks = 0; ks < 16; ++ks) {
          const int off = ((ks * 2 + h) ^ q5) << 3;
          short8 kf0 = *(const short8*)(kr0 + off);
          short8 kf1 = *(const short8*)(kr1 + off);
          acc0 = __builtin_amdgcn_mfma_f32_32x32x16_bf16(kf0, qf[ks], acc0, 0, 0, 0);
          acc1 = __builtin_amdgcn_mfma_f32_32x32x16_bf16(kf1, qf[ks], acc1, 0, 0, 0);
        }
        // key for reg j: ktb + 32*half + (j&3) + 8*(j>>2) + 4h; mask via bit test
        const unsigned wm0 = (unsigned)(mwt >> (4 * h));
        const unsigned wm1 = (unsigned)(mwt >> (32 + 4 * h));
        const int jb = ktb + 4 * h;
#pragma unroll
        for (int j = 0; j < 16; ++j) {
          const int P = (j & 3) + 8 * (j >> 2);
          const bool k0 = (((wm0 >> P) & 1u) != 0u) && (jb + P <= qrow);
          const bool k1 = (((wm1 >> P) & 1u) != 0u) && (jb + 32 + P <= qrow);
          acc0[j] = k0 ? acc0[j] * 0.0625f : NEGF;
          acc1[j] = k1 ? acc1[j] * 0.0625f : NEGF;
        }
      }

      // ---- online softmax: per-lane q-row, reduce 32 + one xor32 (in place)
      {
        float a[16];
#pragma unroll
        for (int j = 0; j < 16; ++j) a[j] = fmaxf(acc0[j], acc1[j]);
#pragma unroll
        for (int j = 0; j < 8; ++j)  a[j] = fmaxf(a[j], a[j + 8]);
#pragma unroll
        for (int j = 0; j < 4; ++j)  a[j] = fmaxf(a[j], a[j + 4]);
        float mx = fmaxf(fmaxf(a[0], a[1]), fmaxf(a[2], a[3]));
        mx = fmaxf(mx, __shfl_xor(mx, 32, 64));
        const float mnew  = fmaxf(m, mx);
        const float alpha = __expf(m - mnew);   // NEGF-NEGF=0 -> 1; NEGF-real -> 0
#pragma unroll
        for (int j = 0; j < 16; ++j) {
          acc0[j] = __expf(acc0[j] - mnew);
          acc1[j] = __expf(acc1[j] - mnew);
        }
        float sa[8];
#pragma unroll
        for (int j = 0; j < 8; ++j)
          sa[j] = (acc0[j] + acc0[j + 8]) + (acc1[j] + acc1[j + 8]);
#pragma unroll
        for (int j = 0; j < 4; ++j) sa[j] += sa[j + 4];
        float ps = (sa[0] + sa[1]) + (sa[2] + sa[3]);
        ps += __shfl_xor(ps, 32, 64);
        l = l * alpha + ps;
        m = mnew;
        if (__ballot(alpha < 1.0f)) {   // alpha is lane-local (q = lane&31)
#pragma unroll
          for (int cb = 0; cb < 8; ++cb)
#pragma unroll
            for (int e = 0; e < 16; ++e) Oa[cb][e] *= alpha;
        }
      }

      // ---- P (S^T C-layout) -> four PV B-frags via 4 xor32 shuffles each
      // kb=0: acc0[0..7], kb=1: acc0[8..15], kb=2: acc1[0..7], kb=3: acc1[8..15]
      short8 pa[4];
#pragma unroll
      for (int kb = 0; kb < 4; ++kb) {
        const f32x16& pp = (kb < 2) ? acc0 : acc1;
        const int bo = (kb & 1) * 8;
        const unsigned a0 = pk2(pp[bo + 0], pp[bo + 1]);
        const unsigned a1 = pk2(pp[bo + 2], pp[bo + 3]);
        const unsigned b0 = pk2(pp[bo + 4], pp[bo + 5]);
        const unsigned b1 = pk2(pp[bo + 6], pp[bo + 7]);
        const unsigned xa0 = (unsigned)__shfl_xor((int)a0, 32, 64);
        const unsigned xa1 = (unsigned)__shfl_xor((int)a1, 32, 64);
        const unsigned xb0 = (unsigned)__shfl_xor((int)b0, 32, 64);
        const unsigned xb1 = (unsigned)__shfl_xor((int)b1, 32, 64);
        S8 f;
        f.w[0] = h ? xb0 : a0;    // elems 0,1: from half-0 lanes
        f.w[1] = h ? xb1 : a1;    // elems 2,3
        f.w[2] = h ? b0 : xa0;    // elems 4,5: from half-1 lanes
        f.w[3] = h ? b1 : xa1;    // elems 6,7
        pa[kb] = f.v;
      }

      // ---- PV: O^T[c][q] += V^T[c][k] P^T[k][q]
#pragma unroll
      for (int cb = 0; cb < 8; ++cb) {
        const short* vb = &VtD[ibuf][(cb * 32 + q5) * 64];
#pragma unroll
        for (int kb = 0; kb < 4; ++kb) {
          short8 vf = *(const short8*)(vb + (((kb * 2 + h) ^ (q5 & 7)) << 3));
          Oa[cb] = __builtin_amdgcn_mfma_f32_32x32x16_bf16(vf, pa[kb], Oa[cb], 0, 0, 0);
        }
      }
    }

    __syncthreads();   // drains this iteration's prefetch (issued a full tile ago)
  } // kt

  // ---- finalize: once per wave, no LDS needed.
  // Lane holds q = lane&31; c set = {cb*32 + (reg&3) + 8*(reg>>2) + 4h}.
  {
    const float li = 1.0f / l;
    const bool dead = (m < -1.0e9f);
#pragma unroll
    for (int cb = 0; cb < 8; ++cb)
#pragma unroll
      for (int e = 0; e < 16; ++e) Oa[cb][e] *= li;
    if (__ballot(dead)) {
      if (dead) {   // fully-masked row -> uniform softmax -> colsum/T
#pragma unroll
        for (int cb = 0; cb < 8; ++cb)
#pragma unroll
          for (int rq = 0; rq < 4; ++rq) {
            float4 cs4 = *(const float4*)(colsum + b * C_ + cb * 32 + rq * 8 + 4 * h);
            Oa[cb][rq * 4 + 0] = cs4.x * (1.0f / T_);
            Oa[cb][rq * 4 + 1] = cs4.y * (1.0f / T_);
            Oa[cb][rq * 4 + 2] = cs4.z * (1.0f / T_);
            Oa[cb][rq * 4 + 3] = cs4.w * (1.0f / T_);
          }
      }
    }
    // LN stats: per-lane partial + xor32 (other half holds the other 128 c's)
    float s1 = 0.f;
#pragma unroll
    for (int cb = 0; cb < 8; ++cb)
#pragma unroll
      for (int e = 0; e < 16; ++e) s1 += Oa[cb][e];
    s1 += __shfl_xor(s1, 32, 64);
    const float mu = s1 * (1.0f / C_);
    float s2 = 0.f;
#pragma unroll
    for (int cb = 0; cb < 8; ++cb)
#pragma unroll
      for (int e = 0; e < 16; ++e) { float d = Oa[cb][e] - mu; s2 += d * d; }
    s2 += __shfl_xor(s2, 32, 64);
    const float rstd = rsqrtf(s2 * (1.0f / C_) + LN_EPS);

    // LN + gamma/beta, then sum over the wave's 32 q per c:
    // DPP tree (xor1, xor2, ror4, ror8 -> 16-lane sums) + xor16 -> 32-lane sum,
    // then one owner lane per (id, half) atomically accumulates.
#pragma unroll
    for (int cb = 0; cb < 8; ++cb) {
#pragma unroll
      for (int rq = 0; rq < 4; ++rq) {
        const int cb4 = cb * 32 + rq * 8 + 4 * h;
        float4 g4 = *(const float4*)(gamma + cb4);
        float4 b4 = *(const float4*)(beta + cb4);
        const float ga[4] = {g4.x, g4.y, g4.z, g4.w};
        const float bb[4] = {b4.x, b4.y, b4.z, b4.w};
#pragma unroll
        for (int e2 = 0; e2 < 4; ++e2) {
          float v = ga[e2] * (Oa[cb][rq * 4 + e2] - mu) * rstd + bb[e2];
          v = DPPADD(v, 0xB1);    // quad_perm [1,0,3,2]  (xor 1)
          v = DPPADD(v, 0x4E);    // quad_perm [2,3,0,1]  (xor 2)
          v = DPPADD(v, 0x124);   // row_ror:4
          v = DPPADD(v, 0x128);   // row_ror:8  -> 16-lane sums everywhere
          v += __shfl_xor(v, 16, 64);   // -> 32-lane (half) sums everywhere
          const int id = cb * 16 + rq * 4 + e2;
          if ((lane & 31) == (id & 15))
            atomicAdd(&accum[b * C_ + cb4 + e2], v);
        }
      }
    }
  }
}

// ---------------- launch ----------------

extern "C" void kernel_launch(void* const* d_in, const int* in_sizes, int n_in,
                              void* d_out, int out_size, void* d_ws, size_t ws_size,
                              hipStream_t stream) {
  const float* x     = (const float*)d_in[0];
  const void*  km    = d_in[1];
  const float* gamma = (const float*)d_in[2];
  const float* beta  = (const float*)d_in[3];
  float* out = (float*)d_out;

  // ws layout
  const size_t off_mk = 131200;                       // u64[B*16] = 8 KB
  const size_t off_xk = 655616;                       // 32 MB bf16 K-image
  const size_t off_xv = off_xk + 33554432;            // 32 MB bf16 V^T-image

  float*              accum  = (float*)d_ws;
  float*              colsum = (float*)((char*)d_ws + 65536);
  int*                flag   = (int*)((char*)d_ws + 131072);
  unsigned long long* mk     = (unsigned long long*)((char*)d_ws + off_mk);
  short*              xk     = (short*)((char*)d_ws + off_xk);
  short*              xv     = (short*)((char*)d_ws + off_xv);

  hipMemsetAsync(d_ws, 0, 131136, stream);   // accum + colsum + flag
  detect_kernel<<<64, 256, 0, stream>>>((const unsigned int*)km, flag);
  mask64_kernel<<<256, 256, 0, stream>>>((const unsigned int*)km, flag, mk);
  convert_kv<<<B_ * 32, 256, 0, stream>>>(x, xk, xv, colsum);
  flash6<<<256, 512, 0, stream>>>(xk, xv, mk, gamma, beta, colsum, accum);
  finalize_kernel<<<B_ * C_ / 256, 256, 0, stream>>>(accum, out);
}

// Round 3
// 216.884 us; speedup vs baseline: 1.1268x; 1.1268x over previous
//
#include <hip/hip_runtime.h>

#define B_   64
#define T_   1024
#define C_   256
#define NEGF (-4294967295.0f)   // float(-2**32+1) == -2^32, matches reference fp32 cast
#define LN_EPS 1e-9f

typedef short  short8 __attribute__((ext_vector_type(8)));
typedef float  f32x16 __attribute__((ext_vector_type(16)));

union S8 { short8 v; unsigned int w[4]; };

// float -> bf16 (RNE), packed pair
__device__ __forceinline__ unsigned int pk2(float x, float y) {
  unsigned a = __float_as_uint(x); a = (a + 0x7fffu + ((a >> 16) & 1u)) >> 16;
  unsigned b = __float_as_uint(y); b = (b + 0x7fffu + ((b >> 16) & 1u)) >> 16;
  return a | (b << 16);
}

// async global->LDS, 16 B per lane
__device__ __forceinline__ void async16(const void* g, void* l) {
  __builtin_amdgcn_global_load_lds(
      (const __attribute__((address_space(1))) void*)g,
      (__attribute__((address_space(3))) void*)l,
      16, 0, 0);
}

// v += dpp-permuted(v); ctrl must be a literal
#define DPPADD(v, ctrl) \
  ((v) + __int_as_float(__builtin_amdgcn_update_dpp( \
      0, __float_as_int(v), (ctrl), 0xF, 0xF, true)))

// ---------------- small kernels ----------------

__global__ void detect_kernel(const unsigned int* __restrict__ mw,
                              int* __restrict__ flag) {
  int idx = blockIdx.x * 256 + threadIdx.x;   // 16384 words, safe for u8 or i32 buffer
  if (mw[idx] > 1u) atomicOr(flag, 1);
}

// one 64-bit key-mask word per (batch, 64-key tile)
__global__ void mask64_kernel(const unsigned int* __restrict__ mw,
                              const int* __restrict__ flag,
                              unsigned long long* __restrict__ mk) {
  int wid  = (blockIdx.x * 256 + threadIdx.x) >> 6;   // 0..1023
  int lane = threadIdx.x & 63;
  int g = wid * 64 + lane;                            // b*1024 + t
  int f = *flag;
  unsigned int wv = mw[f ? (g >> 2) : g];
  unsigned int v  = f ? ((wv >> ((g & 3) * 8)) & 0xffu) : wv;
  unsigned long long bal = __ballot(v != 0);
  if (lane == 0) mk[wid] = bal;
}

__global__ void finalize_kernel(const float* __restrict__ accum,
                                float* __restrict__ out) {
  int idx = blockIdx.x * 256 + threadIdx.x;   // B*C = 16384
  out[idx] = accum[idx] * (1.0f / T_);
}

// ---------------- pre-pass: bf16 K image + V^T image + colsum ----------------
// One block per (b, 32-row tile); x read exactly once via LDS staging.
// K image: row-major [row][256], 16B slot ck stored at ck ^ (row&31).
// V^T image: [b][tile16][c][64 keys], 16B slot j (8 keys) stored at j ^ (c&7).
__global__ __launch_bounds__(256) void convert_kv(const float* __restrict__ x,
                                                  short* __restrict__ xk,
                                                  short* __restrict__ xv,
                                                  float* __restrict__ colsum) {
  __shared__ float Xt[32 * 256];     // 32 KB fp32 tile [j][c]
  __shared__ float csum[4][256];     // 4 KB colsum partials
  const int blk = blockIdx.x, b = blk >> 5, tt = blk & 31;
  const int tid = threadIdx.x;
  const float* xt = x + (size_t)(b * 1024 + tt * 32) * 256;

  // phase 1: coalesced row reads -> LDS fp32 + swizzled bf16 K-image
#pragma unroll
  for (int u = 0; u < 4; ++u) {
    int id = u * 256 + tid;            // 1024 items: 32 rows x 32 chunks
    int row = id >> 5, ck = id & 31;
    const float* src = xt + row * 256 + ck * 8;
    float4 a  = *(const float4*)src;
    float4 c4 = *(const float4*)(src + 4);
    *(float4*)&Xt[row * 256 + ck * 8]     = a;
    *(float4*)&Xt[row * 256 + ck * 8 + 4] = c4;
    S8 s; s.w[0] = pk2(a.x, a.y);  s.w[1] = pk2(a.z, a.w);
          s.w[2] = pk2(c4.x, c4.y); s.w[3] = pk2(c4.z, c4.w);
    *(short8*)(xk + (size_t)(b * 1024 + tt * 32 + row) * 256 + ((ck ^ row) << 3)) = s.v;
  }
  __syncthreads();

  // phase 2: transpose from LDS -> swizzled V^T image + colsum partials
  const int ck = tid >> 6, clo = tid & 63;
  short* vout = xv + (size_t)(b * 16 + (tt >> 1)) * 16384;
  const int jj = (tt & 1) * 4 + ck;      // 8-key block within 64-key tile
#pragma unroll
  for (int g = 0; g < 4; ++g) {
    int c = g * 64 + clo;
    float vs[8]; float s = 0.f;
#pragma unroll
    for (int e = 0; e < 8; ++e) { vs[e] = Xt[(ck * 8 + e) * 256 + c]; s += vs[e]; }
    S8 o;
    o.w[0] = pk2(vs[0], vs[1]); o.w[1] = pk2(vs[2], vs[3]);
    o.w[2] = pk2(vs[4], vs[5]); o.w[3] = pk2(vs[6], vs[7]);
    *(short8*)(vout + (size_t)c * 64 + ((jj ^ (c & 7)) << 3)) = o.v;
    csum[ck][c] = s;
  }
  __syncthreads();
  if (tid < 256) {
    float s = csum[0][tid] + csum[1][tid] + csum[2][tid] + csum[3][tid];
    atomicAdd(&colsum[b * 256 + tid], s);
  }
}

// ---------------- flash kernel (32x32x16 MFMA, 32 q-rows/wave) ----------------
// 256 blocks x 512 threads, 1 block/CU, 128 KB LDS.
// Waves 0-3 own q-tile t, waves 4-7 own q-tile 7-t (concurrent); wave owns
// 32 q rows for the whole kernel. Per 64-key tile: TWO sequential 32-key
// halves, each {QK chain -> mask -> online softmax -> 2x(pack+PV)} so only
// one f32x16 score accumulator is live (spill avoidance vs round-2 version).
// Scores as S^T (D cols = q), output as O^T = V^T P^T -> softmax lane-local.
// XOR-folded LDS addressing: per-lane KE/VE consts, reads = base ^ literal
// with half/cb selector in the ds_read immediate offset.
__global__ __launch_bounds__(512, 2) void flash7(
    const short* __restrict__ xk,
    const short* __restrict__ xv,
    const unsigned long long* __restrict__ mk,
    const float* __restrict__ gamma,
    const float* __restrict__ beta,
    const float* __restrict__ colsum,
    float* __restrict__ accum)
{
  __shared__ __align__(16) short KsD[2][64 * 256];   // 2 x 32 KB  K rows
  __shared__ __align__(16) short VtD[2][256 * 64];   // 2 x 32 KB  V^T [c][64k]

  const int i0 = blockIdx.x;
  const int x8 = i0 & 7;            // XCD id (heuristic: round-robin dispatch)
  const int s  = i0 >> 3;           // 0..31
  const int b  = x8 + 8 * (s & 7);  // batches = x8 (mod 8) cluster on XCD x8
  const int t  = s >> 3;            // 0..3 -> q-tile pair (t, 7-t)

  const int tid  = threadIdx.x;
  const int w    = tid >> 6;        // 0..7
  const int lane = tid & 63;
  const int h    = lane >> 5;       // lane half
  const int q5   = lane & 31;

  const int qt   = (w < 4) ? t : (7 - t);
  const int n0   = qt * 128 + (w & 3) * 32;
  const int qrow = n0 + q5;
  const int nt   = 16 - 2 * t;            // key tiles for this block
  const int last_act = (n0 + 31) >> 6;    // wave's last causally-active tile

  // per-lane XOR-folded LDS address constants (byte offsets)
  // K read: ibuf*32768 + half*16384(imm) + [KE ^ (ks<<5)]
  const int KE = q5 * 512 + ((h ^ (q5 & 1)) << 4) + ((q5 >> 1) << 5);
  // V read: ibuf*32768 + cb*4096(imm) + [VE ^ (kbg<<5)]
  const int VE = q5 * 128 + ((h ^ (q5 & 1)) << 4) + (((q5 >> 1) & 3) << 5);

  // Q fragments: B-operand, lane holds Q[q = n0+q5][ks*16 + 8h + e]
  short8 qf[16];
  {
    const short* qp = xk + (size_t)(b * 1024 + qrow) * 256;
#pragma unroll
    for (int ks = 0; ks < 16; ++ks)
      qf[ks] = *(const short8*)(qp + (((ks * 2 + h) ^ q5) << 3));
  }

  f32x16 Oa[8];                     // O^T accum: row c = cb*32+(reg&3)+8*(reg>>2)+4h, col q
#pragma unroll
  for (int cb = 0; cb < 8; ++cb)
#pragma unroll
    for (int e = 0; e < 16; ++e) Oa[cb][e] = 0.f;

  // prefetch tile 0 into buf 0 (32 KB K + 32 KB V, linear DMA)
  {
    const short* gk = xk + (size_t)b * 1024 * 256;
    const short* gv = xv + (size_t)b * 16 * 16384;
#pragma unroll
    for (int u = 0; u < 4; ++u) {
      const int seg = w * 4 + u;    // 0..31, 1 KB each
      async16(gk + seg * 512 + lane * 8, &KsD[0][seg * 512]);
      async16(gv + seg * 512 + lane * 8, &VtD[0][seg * 512]);
    }
  }

  float m = NEGF, l = 0.f;
  __syncthreads();

  for (int kt = 0; kt < nt; ++kt) {
    const int ibuf = kt & 1;
    if (kt + 1 < nt) {              // async prefetch next tile into other buffer
      const short* gk = xk + (size_t)(b * 1024 + (kt + 1) * 64) * 256;
      const short* gv = xv + (size_t)(b * 16 + kt + 1) * 16384;
#pragma unroll
      for (int u = 0; u < 4; ++u) {
        const int seg = w * 4 + u;
        async16(gk + seg * 512 + lane * 8, &KsD[1 - ibuf][seg * 512]);
        async16(gv + seg * 512 + lane * 8, &VtD[1 - ibuf][seg * 512]);
      }
    }

    if (kt <= last_act) {           // wave-uniform causal tile skip
      const int ktb = kt * 64;
      const unsigned long long mwt = mk[b * 16 + kt];
      const int kadr = ibuf * 32768 + KE;
      const int vadr = ibuf * 32768 + VE;

#pragma unroll
      for (int half = 0; half < 2; ++half) {
        // ---- scores S^T = K·Q^T for this 32-key half (16-MFMA chain)
        f32x16 acc;
#pragma unroll
        for (int e = 0; e < 16; ++e) acc[e] = 0.f;
        __builtin_amdgcn_s_setprio(1);
#pragma unroll
        for (int ks = 0; ks < 16; ++ks) {
          short8 kf = *(const short8*)((const char*)KsD +
                        ((kadr ^ (ks << 5)) + half * 16384));
          acc = __builtin_amdgcn_mfma_f32_32x32x16_bf16(kf, qf[ks], acc, 0, 0, 0);
        }
        __builtin_amdgcn_s_setprio(0);

        // ---- mask: combined keymask & causal, pre-shifted by 4h; reg j holds
        // within-half key (j&3) + 8*(j>>2) + 4h
        {
          unsigned kmsk = (unsigned)(mwt >> (32 * half));
          int qd = qrow - (ktb + 32 * half);
          unsigned cm = (qd >= 31) ? 0xffffffffu
                                   : ((qd < 0) ? 0u : ((2u << qd) - 1u));
          unsigned amh = (kmsk & cm) >> (4 * h);
#pragma unroll
          for (int j = 0; j < 16; ++j) {
            const int P = (j & 3) + 8 * (j >> 2);
            acc[j] = ((amh >> P) & 1u) ? acc[j] * 0.0625f : NEGF;
          }
        }

        // ---- online softmax (q = lane&31 is lane-local; one xor32 per stat)
        {
          float t0 = fmaxf(fmaxf(acc[0], acc[1]),  fmaxf(acc[2], acc[3]));
          float t1 = fmaxf(fmaxf(acc[4], acc[5]),  fmaxf(acc[6], acc[7]));
          float t2 = fmaxf(fmaxf(acc[8], acc[9]),  fmaxf(acc[10], acc[11]));
          float t3 = fmaxf(fmaxf(acc[12], acc[13]), fmaxf(acc[14], acc[15]));
          float mx = fmaxf(fmaxf(t0, t1), fmaxf(t2, t3));
          mx = fmaxf(mx, __shfl_xor(mx, 32, 64));
          const float mnew  = fmaxf(m, mx);
          const float alpha = __expf(m - mnew);   // NEGF-NEGF=0 -> 1
#pragma unroll
          for (int j = 0; j < 16; ++j) acc[j] = __expf(acc[j] - mnew);
          float s0 = (acc[0] + acc[1])  + (acc[2] + acc[3]);
          float s1 = (acc[4] + acc[5])  + (acc[6] + acc[7]);
          float s2 = (acc[8] + acc[9])  + (acc[10] + acc[11]);
          float s3 = (acc[12] + acc[13]) + (acc[14] + acc[15]);
          float ps = (s0 + s1) + (s2 + s3);
          ps += __shfl_xor(ps, 32, 64);
          l = l * alpha + ps;
          m = mnew;
          if (__ballot(alpha < 1.0f)) {   // alpha lane-local per q
#pragma unroll
            for (int cb = 0; cb < 8; ++cb)
#pragma unroll
              for (int e = 0; e < 16; ++e) Oa[cb][e] *= alpha;
          }
        }

        // ---- two 16-key blocks: pack one B-frag, consume in 8 MFMAs
#pragma unroll
        for (int kb = 0; kb < 2; ++kb) {
          short8 pa;
          {
            const unsigned a0 = pk2(acc[kb * 8 + 0], acc[kb * 8 + 1]);
            const unsigned a1 = pk2(acc[kb * 8 + 2], acc[kb * 8 + 3]);
            const unsigned b0 = pk2(acc[kb * 8 + 4], acc[kb * 8 + 5]);
            const unsigned b1 = pk2(acc[kb * 8 + 6], acc[kb * 8 + 7]);
            const unsigned xa0 = (unsigned)__shfl_xor((int)a0, 32, 64);
            const unsigned xa1 = (unsigned)__shfl_xor((int)a1, 32, 64);
            const unsigned xb0 = (unsigned)__shfl_xor((int)b0, 32, 64);
            const unsigned xb1 = (unsigned)__shfl_xor((int)b1, 32, 64);
            S8 f;
            f.w[0] = h ? xb0 : a0;    // elems 0,1: from half-0 lanes
            f.w[1] = h ? xb1 : a1;    // elems 2,3
            f.w[2] = h ? b0 : xa0;    // elems 4,5: from half-1 lanes
            f.w[3] = h ? b1 : xa1;    // elems 6,7
            pa = f.v;
          }
          const int kbg = half * 2 + kb;
          const int vx  = vadr ^ (kbg << 5);
          __builtin_amdgcn_s_setprio(1);
#pragma unroll
          for (int cb = 0; cb < 8; ++cb) {
            short8 vf = *(const short8*)((const char*)VtD + (vx + cb * 4096));
            Oa[cb] = __builtin_amdgcn_mfma_f32_32x32x16_bf16(vf, pa, Oa[cb], 0, 0, 0);
          }
          __builtin_amdgcn_s_setprio(0);
        }
      } // half
    }

    __syncthreads();   // drains this iteration's prefetch (issued a full tile ago)
  } // kt

  // ---- finalize: once per wave, no LDS needed.
  // Lane holds q = lane&31; c set = {cb*32 + (reg&3) + 8*(reg>>2) + 4h}.
  {
    const float li = 1.0f / l;
    const bool dead = (m < -1.0e9f);
#pragma unroll
    for (int cb = 0; cb < 8; ++cb)
#pragma unroll
      for (int e = 0; e < 16; ++e) Oa[cb][e] *= li;
    if (__ballot(dead)) {
      if (dead) {   // fully-masked row -> uniform softmax -> colsum/T
#pragma unroll
        for (int cb = 0; cb < 8; ++cb)
#pragma unroll
          for (int rq = 0; rq < 4; ++rq) {
            float4 cs4 = *(const float4*)(colsum + b * C_ + cb * 32 + rq * 8 + 4 * h);
            Oa[cb][rq * 4 + 0] = cs4.x * (1.0f / T_);
            Oa[cb][rq * 4 + 1] = cs4.y * (1.0f / T_);
            Oa[cb][rq * 4 + 2] = cs4.z * (1.0f / T_);
            Oa[cb][rq * 4 + 3] = cs4.w * (1.0f / T_);
          }
      }
    }
    // LN stats: per-lane partial + xor32 (other half holds the other 128 c's)
    float s1 = 0.f;
#pragma unroll
    for (int cb = 0; cb < 8; ++cb)
#pragma unroll
      for (int e = 0; e < 16; ++e) s1 += Oa[cb][e];
    s1 += __shfl_xor(s1, 32, 64);
    const float mu = s1 * (1.0f / C_);
    float s2 = 0.f;
#pragma unroll
    for (int cb = 0; cb < 8; ++cb)
#pragma unroll
      for (int e = 0; e < 16; ++e) { float d = Oa[cb][e] - mu; s2 += d * d; }
    s2 += __shfl_xor(s2, 32, 64);
    const float rstd = rsqrtf(s2 * (1.0f / C_) + LN_EPS);

    // LN + gamma/beta, then sum over the wave's 32 q per c:
    // DPP tree (xor1, xor2, ror4, ror8 -> 16-lane sums) + xor16 -> 32-lane sum,
    // then one owner lane per (id, half) atomically accumulates.
#pragma unroll
    for (int cb = 0; cb < 8; ++cb) {
#pragma unroll
      for (int rq = 0; rq < 4; ++rq) {
        const int cb4 = cb * 32 + rq * 8 + 4 * h;
        float4 g4 = *(const float4*)(gamma + cb4);
        float4 b4 = *(const float4*)(beta + cb4);
        const float ga[4] = {g4.x, g4.y, g4.z, g4.w};
        const float bb[4] = {b4.x, b4.y, b4.z, b4.w};
#pragma unroll
        for (int e2 = 0; e2 < 4; ++e2) {
          float v = ga[e2] * (Oa[cb][rq * 4 + e2] - mu) * rstd + bb[e2];
          v = DPPADD(v, 0xB1);    // quad_perm [1,0,3,2]  (xor 1)
          v = DPPADD(v, 0x4E);    // quad_perm [2,3,0,1]  (xor 2)
          v = DPPADD(v, 0x124);   // row_ror:4
          v = DPPADD(v, 0x128);   // row_ror:8  -> 16-lane sums everywhere
          v += __shfl_xor(v, 16, 64);   // -> 32-lane (half) sums everywhere
          const int id = cb * 16 + rq * 4 + e2;
          if ((lane & 31) == (id & 15))
            atomicAdd(&accum[b * C_ + cb4 + e2], v);
        }
      }
    }
  }
}

// ---------------- launch ----------------

extern "C" void kernel_launch(void* const* d_in, const int* in_sizes, int n_in,
                              void* d_out, int out_size, void* d_ws, size_t ws_size,
                              hipStream_t stream) {
  const float* x     = (const float*)d_in[0];
  const void*  km    = d_in[1];
  const float* gamma = (const float*)d_in[2];
  const float* beta  = (const float*)d_in[3];
  float* out = (float*)d_out;

  // ws layout
  const size_t off_mk = 131200;                       // u64[B*16] = 8 KB
  const size_t off_xk = 655616;                       // 32 MB bf16 K-image
  const size_t off_xv = off_xk + 33554432;            // 32 MB bf16 V^T-image

  float*              accum  = (float*)d_ws;
  float*              colsum = (float*)((char*)d_ws + 65536);
  int*                flag   = (int*)((char*)d_ws + 131072);
  unsigned long long* mk     = (unsigned long long*)((char*)d_ws + off_mk);
  short*              xk     = (short*)((char*)d_ws + off_xk);
  short*              xv     = (short*)((char*)d_ws + off_xv);

  hipMemsetAsync(d_ws, 0, 131136, stream);   // accum + colsum + flag
  detect_kernel<<<64, 256, 0, stream>>>((const unsigned int*)km, flag);
  mask64_kernel<<<256, 256, 0, stream>>>((const unsigned int*)km, flag, mk);
  convert_kv<<<B_ * 32, 256, 0, stream>>>(x, xk, xv, colsum);
  flash7<<<256, 512, 0, stream>>>(xk, xv, mk, gamma, beta, colsum, accum);
  finalize_kernel<<<B_ * C_ / 256, 256, 0, stream>>>(accum, out);
}

// Round 4
// 202.079 us; speedup vs baseline: 1.2094x; 1.0733x over previous
//
#include <hip/hip_runtime.h>

#define B_   64
#define T_   1024
#define C_   256
#define NEGF (-4294967295.0f)   // float(-2**32+1) == -2^32, matches reference fp32 cast
#define LN_EPS 1e-9f

typedef short  short8 __attribute__((ext_vector_type(8)));
typedef float  f32x16 __attribute__((ext_vector_type(16)));

union S8 { short8 v; unsigned int w[4]; };

// float -> bf16 (RNE), packed pair
__device__ __forceinline__ unsigned int pk2(float x, float y) {
  unsigned a = __float_as_uint(x); a = (a + 0x7fffu + ((a >> 16) & 1u)) >> 16;
  unsigned b = __float_as_uint(y); b = (b + 0x7fffu + ((b >> 16) & 1u)) >> 16;
  return a | (b << 16);
}

// async global->LDS, 16 B per lane
__device__ __forceinline__ void async16(const void* g, void* l) {
  __builtin_amdgcn_global_load_lds(
      (const __attribute__((address_space(1))) void*)g,
      (__attribute__((address_space(3))) void*)l,
      16, 0, 0);
}

// v += dpp-permuted(v); ctrl must be a literal
#define DPPADD(v, ctrl) \
  ((v) + __int_as_float(__builtin_amdgcn_update_dpp( \
      0, __float_as_int(v), (ctrl), 0xF, 0xF, true)))

// ---------------- small kernels ----------------

__global__ void detect_kernel(const unsigned int* __restrict__ mw,
                              int* __restrict__ flag) {
  int idx = blockIdx.x * 256 + threadIdx.x;   // 16384 words, safe for u8 or i32 buffer
  if (mw[idx] > 1u) atomicOr(flag, 1);
}

// one 64-bit key-mask word per (batch, 64-key tile)
__global__ void mask64_kernel(const unsigned int* __restrict__ mw,
                              const int* __restrict__ flag,
                              unsigned long long* __restrict__ mk) {
  int wid  = (blockIdx.x * 256 + threadIdx.x) >> 6;   // 0..1023
  int lane = threadIdx.x & 63;
  int g = wid * 64 + lane;                            // b*1024 + t
  int f = *flag;
  unsigned int wv = mw[f ? (g >> 2) : g];
  unsigned int v  = f ? ((wv >> ((g & 3) * 8)) & 0xffu) : wv;
  unsigned long long bal = __ballot(v != 0);
  if (lane == 0) mk[wid] = bal;
}

__global__ void finalize_kernel(const float* __restrict__ accum,
                                float* __restrict__ out) {
  int idx = blockIdx.x * 256 + threadIdx.x;   // B*C = 16384
  out[idx] = accum[idx] * (1.0f / T_);
}

// ---------------- pre-pass: bf16 K image + V^T image + colsum ----------------
// One block per (b, 32-row tile); x read exactly once via LDS staging.
// K image: row-major [row][256], 16B slot ck stored at ck ^ (row&31).
// V^T image: [b][tile32][c][32 keys], 16B slot s stored at s ^ ((c>>1)&3).
// V^T tile staged in LDS then written with fully-coalesced linear stores
// (the old direct path scattered 16B stores at 64B stride -> uncoalesced).
__global__ __launch_bounds__(256) void convert_kv(const float* __restrict__ x,
                                                  short* __restrict__ xk,
                                                  short* __restrict__ xv,
                                                  float* __restrict__ colsum) {
  __shared__ float Xt[32 * 256];             // 32 KB fp32 tile [j][c]
  __shared__ __align__(16) short Vt[8192];   // 16 KB staged V^T tile
  __shared__ float csum[4][256];             // 4 KB colsum partials
  const int blk = blockIdx.x, b = blk >> 5, tt = blk & 31;
  const int tid = threadIdx.x;
  const float* xt = x + (size_t)(b * 1024 + tt * 32) * 256;

  // phase 1: coalesced row reads -> LDS fp32 + swizzled bf16 K-image
#pragma unroll
  for (int u = 0; u < 4; ++u) {
    int id = u * 256 + tid;            // 1024 items: 32 rows x 32 chunks
    int row = id >> 5, ck = id & 31;
    const float* src = xt + row * 256 + ck * 8;
    float4 a  = *(const float4*)src;
    float4 c4 = *(const float4*)(src + 4);
    *(float4*)&Xt[row * 256 + ck * 8]     = a;
    *(float4*)&Xt[row * 256 + ck * 8 + 4] = c4;
    S8 s; s.w[0] = pk2(a.x, a.y);  s.w[1] = pk2(a.z, a.w);
          s.w[2] = pk2(c4.x, c4.y); s.w[3] = pk2(c4.z, c4.w);
    *(short8*)(xk + (size_t)(b * 1024 + tt * 32 + row) * 256 + ((ck ^ row) << 3)) = s.v;
  }
  __syncthreads();

  // phase 2: transpose from LDS -> staged V^T tile (LDS) + colsum partials
  const int ck = tid >> 6, clo = tid & 63;
#pragma unroll
  for (int g = 0; g < 4; ++g) {
    int c = g * 64 + clo;
    float vs[8]; float s = 0.f;
#pragma unroll
    for (int e = 0; e < 8; ++e) { vs[e] = Xt[(ck * 8 + e) * 256 + c]; s += vs[e]; }
    S8 o;
    o.w[0] = pk2(vs[0], vs[1]); o.w[1] = pk2(vs[2], vs[3]);
    o.w[2] = pk2(vs[4], vs[5]); o.w[3] = pk2(vs[6], vs[7]);
    *(short8*)&Vt[c * 32 + ((ck ^ ((c >> 1) & 3)) << 3)] = o.v;
    csum[ck][c] = s;
  }
  __syncthreads();

  // phase 3: linear coalesced copy-out of V^T tile + colsum reduce
  {
    float4* vo = (float4*)(xv + (size_t)(b * 32 + tt) * 8192);
    const float4* vi = (const float4*)Vt;
#pragma unroll
    for (int r = 0; r < 4; ++r) vo[r * 256 + tid] = vi[r * 256 + tid];
    float s = csum[0][tid] + csum[1][tid] + csum[2][tid] + csum[3][tid];
    atomicAdd(&colsum[b * 256 + tid], s);
  }
}

// ---------------- flash kernel (32x32x16 MFMA, 32 q-rows/wave) ----------------
// 512 blocks x 256 threads (4 waves), 2 blocks/CU, 64 KB LDS each.
// Block = (batch b, q-tile t); the dispatch-order mapping pairs blocks
// (b, t) and (b, 7-t) on the same CU (round-robin heuristic): balanced
// 36 tile-periods/CU, and each block's barrier stalls are hidden by the
// other block's compute. All 4 waves of a block are near-uniformly active
// (wave w active for kt <= 4t+w of 4t+4 tiles). 32-key tiles: K 16KB +
// V^T 16KB double-buffered async DMA, one barrier per tile.
// Scores as S^T (D cols = q), output as O^T = V^T P^T -> softmax lane-local.
// Register budget: Oa 128 + qf 64 + acc 16 + bounded ds_read lookahead
// (sched_group_barrier chunks) ~= 225 < 256 (no spills -> WRITE_SIZE small).
__global__ __launch_bounds__(256, 2) void flash8(
    const short* __restrict__ xk,
    const short* __restrict__ xv,
    const unsigned long long* __restrict__ mk,
    const float* __restrict__ gamma,
    const float* __restrict__ beta,
    const float* __restrict__ colsum,
    float* __restrict__ accum)
{
  __shared__ __align__(16) short KsD[2][32 * 256];   // 2 x 16 KB  K rows
  __shared__ __align__(16) short VtD[2][8192];       // 2 x 16 KB  V^T [c][32k]

  const int i0  = blockIdx.x;
  const int x8  = i0 & 7;           // XCD id (round-robin dispatch heuristic)
  const int s   = i0 >> 3;          // 0..63 within XCD
  const int sec = s >> 5;           // 0: first block on CU, 1: second
  const int j   = s & 31;           // CU index within XCD
  const int b   = x8 + 8 * (j >> 2);          // 8 batches per XCD
  const int t4  = j & 3;
  const int t   = sec ? (7 - t4) : t4;        // CU pair gets (t, 7-t), same b

  const int tid  = threadIdx.x;
  const int w    = tid >> 6;        // 0..3
  const int lane = tid & 63;
  const int h    = lane >> 5;       // lane half
  const int q5   = lane & 31;

  const int n0   = t * 128 + w * 32;
  const int qrow = n0 + q5;
  const int nt   = 4 * (t + 1);     // 32-key tiles for this q-tile
  const int last = 4 * t + w;       // wave's last causally-active tile

  // per-lane XOR-folded LDS byte-address constants
  const int KE = q5 * 512 + ((h ^ q5) << 4);               // ^ (ks<<5)
  const int VE = q5 * 64  + ((h ^ ((q5 >> 1) & 3)) << 4);  // ^ (kb<<5), + cb*2048

  // Q fragments: B-operand, lane holds Q[q = n0+q5][ks*16 + 8h + e]
  short8 qf[16];
  {
    const short* qp = xk + (size_t)(b * 1024 + qrow) * 256;
#pragma unroll
    for (int ks = 0; ks < 16; ++ks)
      qf[ks] = *(const short8*)(qp + (((ks * 2 + h) ^ q5) << 3));
  }

  f32x16 Oa[8];                     // O^T accum: c = cb*32+(reg&3)+8*(reg>>2)+4h, col q
#pragma unroll
  for (int cb = 0; cb < 8; ++cb)
#pragma unroll
    for (int e = 0; e < 16; ++e) Oa[cb][e] = 0.f;

  // prefetch tile 0 into buf 0 (16 KB K + 16 KB V, linear DMA)
  {
    const short* gk = xk + (size_t)(b * 1024) * 256;
    const short* gv = xv + (size_t)(b * 32) * 8192;
#pragma unroll
    for (int u = 0; u < 4; ++u) {
      const int seg = w * 4 + u;    // 0..15, 1 KB each
      async16(gk + seg * 512 + lane * 8, &KsD[0][seg * 512]);
      async16(gv + seg * 512 + lane * 8, &VtD[0][seg * 512]);
    }
  }

  float m = NEGF, l = 0.f;
  __syncthreads();

  for (int kt = 0; kt < nt; ++kt) {
    const int ibuf = kt & 1;
    if (kt + 1 < nt) {              // async prefetch next tile into other buffer
      const short* gk = xk + (size_t)(b * 1024 + (kt + 1) * 32) * 256;
      const short* gv = xv + (size_t)(b * 32 + kt + 1) * 8192;
#pragma unroll
      for (int u = 0; u < 4; ++u) {
        const int seg = w * 4 + u;
        async16(gk + seg * 512 + lane * 8, &KsD[1 - ibuf][seg * 512]);
        async16(gv + seg * 512 + lane * 8, &VtD[1 - ibuf][seg * 512]);
      }
    }

    if (kt <= last) {               // wave-uniform causal tile skip
      const int ktb = kt * 32;
      const unsigned kmsk = ((const unsigned*)mk)[b * 32 + kt];
      const int kbase = ibuf * 16384 + KE;

      // ---- scores S^T = K·Q^T (16-MFMA chain, bounded ds_read lookahead)
      f32x16 acc;
#pragma unroll
      for (int e = 0; e < 16; ++e) acc[e] = 0.f;
      __builtin_amdgcn_s_setprio(1);
#pragma unroll
      for (int ks = 0; ks < 16; ++ks) {
        short8 kf = *(const short8*)((const char*)KsD + (kbase ^ (ks << 5)));
        acc = __builtin_amdgcn_mfma_f32_32x32x16_bf16(kf, qf[ks], acc, 0, 0, 0);
        if ((ks & 1) == 1) {
          __builtin_amdgcn_sched_group_barrier(0x100, 2, 0);  // 2 DS_READ
          __builtin_amdgcn_sched_group_barrier(0x008, 2, 0);  // 2 MFMA
        }
      }
      __builtin_amdgcn_s_setprio(0);

      // ---- mask: keymask & causal; reg j holds key ktb + (j&3)+8*(j>>2)+4h
      {
        const int qd = qrow - ktb;   // >= 0 for active waves
        const unsigned cm  = (qd >= 31) ? 0xffffffffu : ((2u << qd) - 1u);
        const unsigned amh = (kmsk & cm) >> (4 * h);
#pragma unroll
        for (int j2 = 0; j2 < 16; ++j2) {
          const int P = (j2 & 3) + 8 * (j2 >> 2);
          acc[j2] = ((amh >> P) & 1u) ? acc[j2] * 0.0625f : NEGF;
        }
      }

      // ---- online softmax with defer-max (THR=8): skip Oa rescale unless
      // some lane's row-max grew by >8 (T13). q = lane&31 is lane-local.
      {
        float t0 = fmaxf(fmaxf(acc[0], acc[1]),   fmaxf(acc[2], acc[3]));
        float t1 = fmaxf(fmaxf(acc[4], acc[5]),   fmaxf(acc[6], acc[7]));
        float t2 = fmaxf(fmaxf(acc[8], acc[9]),   fmaxf(acc[10], acc[11]));
        float t3 = fmaxf(fmaxf(acc[12], acc[13]), fmaxf(acc[14], acc[15]));
        float mx = fmaxf(fmaxf(t0, t1), fmaxf(t2, t3));
        mx = fmaxf(mx, __shfl_xor(mx, 32, 64));
        if (__ballot(mx > m + 8.f)) {
          const float mnew  = fmaxf(m, mx);
          const float alpha = __expf(m - mnew);   // NEGF-NEGF=0 -> 1
#pragma unroll
          for (int cb = 0; cb < 8; ++cb)
#pragma unroll
            for (int e = 0; e < 16; ++e) Oa[cb][e] *= alpha;
          l *= alpha;
          m = mnew;
        }
#pragma unroll
        for (int j2 = 0; j2 < 16; ++j2) acc[j2] = __expf(acc[j2] - m);
        float s0 = (acc[0] + acc[1])   + (acc[2] + acc[3]);
        float s1 = (acc[4] + acc[5])   + (acc[6] + acc[7]);
        float s2 = (acc[8] + acc[9])   + (acc[10] + acc[11]);
        float s3 = (acc[12] + acc[13]) + (acc[14] + acc[15]);
        float ps = (s0 + s1) + (s2 + s3);
        ps += __shfl_xor(ps, 32, 64);
        l += ps;
      }

      // ---- two 16-key blocks: pack one B-frag (4 xor32 shuffles), 8 MFMAs
      const int vbase = ibuf * 16384 + VE;
#pragma unroll
      for (int kb = 0; kb < 2; ++kb) {
        short8 pa;
        {
          const unsigned a0 = pk2(acc[kb * 8 + 0], acc[kb * 8 + 1]);
          const unsigned a1 = pk2(acc[kb * 8 + 2], acc[kb * 8 + 3]);
          const unsigned b0 = pk2(acc[kb * 8 + 4], acc[kb * 8 + 5]);
          const unsigned b1 = pk2(acc[kb * 8 + 6], acc[kb * 8 + 7]);
          const unsigned xa0 = (unsigned)__shfl_xor((int)a0, 32, 64);
          const unsigned xa1 = (unsigned)__shfl_xor((int)a1, 32, 64);
          const unsigned xb0 = (unsigned)__shfl_xor((int)b0, 32, 64);
          const unsigned xb1 = (unsigned)__shfl_xor((int)b1, 32, 64);
          S8 f;
          f.w[0] = h ? xb0 : a0;    // elems 0,1: from half-0 lanes
          f.w[1] = h ? xb1 : a1;    // elems 2,3
          f.w[2] = h ? b0 : xa0;    // elems 4,5: from half-1 lanes
          f.w[3] = h ? b1 : xa1;    // elems 6,7
          pa = f.v;
        }
        const int vx = vbase ^ (kb << 5);
        __builtin_amdgcn_s_setprio(1);
#pragma unroll
        for (int cb = 0; cb < 8; ++cb) {
          short8 vf = *(const short8*)((const char*)VtD + (vx + cb * 2048));
          Oa[cb] = __builtin_amdgcn_mfma_f32_32x32x16_bf16(vf, pa, Oa[cb], 0, 0, 0);
          if ((cb & 1) == 1) {
            __builtin_amdgcn_sched_group_barrier(0x100, 2, 0);
            __builtin_amdgcn_sched_group_barrier(0x008, 2, 0);
          }
        }
        __builtin_amdgcn_s_setprio(0);
      }
    }

    __syncthreads();   // drains this iteration's prefetch (issued a full tile ago)
  } // kt

  // ---- finalize: once per wave, no LDS needed.
  // Lane holds q = lane&31; c set = {cb*32 + (reg&3) + 8*(reg>>2) + 4h}.
  {
    const float li = 1.0f / l;
    const bool dead = (m < -1.0e9f);
#pragma unroll
    for (int cb = 0; cb < 8; ++cb)
#pragma unroll
      for (int e = 0; e < 16; ++e) Oa[cb][e] *= li;
    if (__ballot(dead)) {
      if (dead) {   // fully-masked row -> uniform softmax -> colsum/T
#pragma unroll
        for (int cb = 0; cb < 8; ++cb)
#pragma unroll
          for (int rq = 0; rq < 4; ++rq) {
            float4 cs4 = *(const float4*)(colsum + b * C_ + cb * 32 + rq * 8 + 4 * h);
            Oa[cb][rq * 4 + 0] = cs4.x * (1.0f / T_);
            Oa[cb][rq * 4 + 1] = cs4.y * (1.0f / T_);
            Oa[cb][rq * 4 + 2] = cs4.z * (1.0f / T_);
            Oa[cb][rq * 4 + 3] = cs4.w * (1.0f / T_);
          }
      }
    }
    // LN stats: per-lane partial + xor32 (other half holds the other 128 c's)
    float s1 = 0.f;
#pragma unroll
    for (int cb = 0; cb < 8; ++cb)
#pragma unroll
      for (int e = 0; e < 16; ++e) s1 += Oa[cb][e];
    s1 += __shfl_xor(s1, 32, 64);
    const float mu = s1 * (1.0f / C_);
    float s2 = 0.f;
#pragma unroll
    for (int cb = 0; cb < 8; ++cb)
#pragma unroll
      for (int e = 0; e < 16; ++e) { float d = Oa[cb][e] - mu; s2 += d * d; }
    s2 += __shfl_xor(s2, 32, 64);
    const float rstd = rsqrtf(s2 * (1.0f / C_) + LN_EPS);

    // LN + gamma/beta, then sum over the wave's 32 q per c:
    // DPP tree (xor1, xor2, ror4, ror8 -> 16-lane sums) + xor16 -> 32-lane sum,
    // then one owner lane per (id, half) atomically accumulates.
#pragma unroll
    for (int cb = 0; cb < 8; ++cb) {
#pragma unroll
      for (int rq = 0; rq < 4; ++rq) {
        const int cb4 = cb * 32 + rq * 8 + 4 * h;
        float4 g4 = *(const float4*)(gamma + cb4);
        float4 b4 = *(const float4*)(beta + cb4);
        const float ga[4] = {g4.x, g4.y, g4.z, g4.w};
        const float bb[4] = {b4.x, b4.y, b4.z, b4.w};
#pragma unroll
        for (int e2 = 0; e2 < 4; ++e2) {
          float v = ga[e2] * (Oa[cb][rq * 4 + e2] - mu) * rstd + bb[e2];
          v = DPPADD(v, 0xB1);    // quad_perm [1,0,3,2]  (xor 1)
          v = DPPADD(v, 0x4E);    // quad_perm [2,3,0,1]  (xor 2)
          v = DPPADD(v, 0x124);   // row_ror:4
          v = DPPADD(v, 0x128);   // row_ror:8  -> 16-lane sums everywhere
          v += __shfl_xor(v, 16, 64);   // -> 32-lane (half) sums everywhere
          const int id = cb * 16 + rq * 4 + e2;
          if ((lane & 31) == (id & 15))
            atomicAdd(&accum[b * C_ + cb4 + e2], v);
        }
      }
    }
  }
}

// ---------------- launch ----------------

extern "C" void kernel_launch(void* const* d_in, const int* in_sizes, int n_in,
                              void* d_out, int out_size, void* d_ws, size_t ws_size,
                              hipStream_t stream) {
  const float* x     = (const float*)d_in[0];
  const void*  km    = d_in[1];
  const float* gamma = (const float*)d_in[2];
  const float* beta  = (const float*)d_in[3];
  float* out = (float*)d_out;

  // ws layout
  const size_t off_mk = 131200;                       // u64[B*16] = 8 KB
  const size_t off_xk = 655616;                       // 32 MB bf16 K-image
  const size_t off_xv = off_xk + 33554432;            // 32 MB bf16 V^T-image

  float*              accum  = (float*)d_ws;
  float*              colsum = (float*)((char*)d_ws + 65536);
  int*                flag   = (int*)((char*)d_ws + 131072);
  unsigned long long* mk     = (unsigned long long*)((char*)d_ws + off_mk);
  short*              xk     = (short*)((char*)d_ws + off_xk);
  short*              xv     = (short*)((char*)d_ws + off_xv);

  hipMemsetAsync(d_ws, 0, 131136, stream);   // accum + colsum + flag
  detect_kernel<<<64, 256, 0, stream>>>((const unsigned int*)km, flag);
  mask64_kernel<<<256, 256, 0, stream>>>((const unsigned int*)km, flag, mk);
  convert_kv<<<B_ * 32, 256, 0, stream>>>(x, xk, xv, colsum);
  flash8<<<512, 256, 0, stream>>>(xk, xv, mk, gamma, beta, colsum, accum);
  finalize_kernel<<<B_ * C_ / 256, 256, 0, stream>>>(accum, out);
}

// Round 6
// 172.267 us; speedup vs baseline: 1.4187x; 1.1731x over previous
//
#include <hip/hip_runtime.h>

#define B_   64
#define T_   1024
#define C_   256
#define NEGF (-4294967295.0f)   // float(-2**32+1) == -2^32, matches reference fp32 cast
#define LN_EPS 1e-9f

typedef short  short8 __attribute__((ext_vector_type(8)));
typedef float  f32x4  __attribute__((ext_vector_type(4)));

union S8 { short8 v; unsigned int w[4]; };

// float -> bf16 (RNE), packed pair
__device__ __forceinline__ unsigned int pk2(float x, float y) {
  unsigned a = __float_as_uint(x); a = (a + 0x7fffu + ((a >> 16) & 1u)) >> 16;
  unsigned b = __float_as_uint(y); b = (b + 0x7fffu + ((b >> 16) & 1u)) >> 16;
  return a | (b << 16);
}

// async global->LDS, 16 B per lane
__device__ __forceinline__ void async16(const void* g, void* l) {
  __builtin_amdgcn_global_load_lds(
      (const __attribute__((address_space(1))) void*)g,
      (__attribute__((address_space(3))) void*)l,
      16, 0, 0);
}

// ---------------- small kernels ----------------

__global__ void detect_kernel(const unsigned int* __restrict__ mw,
                              int* __restrict__ flag) {
  int idx = blockIdx.x * 256 + threadIdx.x;   // 16384 words, safe for u8 or i32 buffer
  if (mw[idx] > 1u) atomicOr(flag, 1);
}

__global__ void finalize_kernel(const float* __restrict__ accum,
                                float* __restrict__ out) {
  int idx = blockIdx.x * 256 + threadIdx.x;   // B*C = 16384
  out[idx] = accum[idx] * (1.0f / T_);
}

// ---------------- pre-pass: bf16 K image + V^T image + colsum + sb ----------------
// One block per (b, 32-row tile); x read exactly once via LDS staging.
// V^T tile staged in LDS then written with fully-coalesced linear float4
// stores (the old direct path scattered 16B stores at 64B stride).
__global__ __launch_bounds__(256) void convert_kv(const float* __restrict__ x,
                                                  const unsigned int* __restrict__ mw,
                                                  const int* __restrict__ flag,
                                                  short* __restrict__ xk,
                                                  short* __restrict__ xv,
                                                  float* __restrict__ colsum,
                                                  float2* __restrict__ sb) {
  __shared__ float Xt[32 * 256];             // 32 KB fp32 tile [j][c]
  __shared__ __align__(16) short Vt[8192];   // 16 KB staged V^T tile
  __shared__ float csum[4][256];             // 4 KB colsum partials
  const int blk = blockIdx.x, b = blk >> 5, tt = blk & 31;
  const int tid = threadIdx.x;
  const float* xt = x + (size_t)(b * 1024 + tt * 32) * 256;

  // sb entries for this block's 32 rows (score = s*scale + bias)
  if (tid < 32) {
    int idx = b * 1024 + tt * 32 + tid;
    int f = *flag;
    unsigned int w = mw[f ? (idx >> 2) : idx];
    unsigned int v = f ? ((w >> ((idx & 3) * 8)) & 0xffu) : w;
    sb[idx] = v ? make_float2(0.0625f, 0.f) : make_float2(0.f, NEGF);
  }

  // phase 1: coalesced row reads -> LDS fp32 + swizzled bf16 K-image
#pragma unroll
  for (int u = 0; u < 4; ++u) {
    int id = u * 256 + tid;            // 1024 items: 32 rows x 32 chunks
    int row = id >> 5, ck = id & 31;
    const float* src = xt + row * 256 + ck * 8;
    float4 a  = *(const float4*)src;
    float4 c4 = *(const float4*)(src + 4);
    *(float4*)&Xt[row * 256 + ck * 8]     = a;
    *(float4*)&Xt[row * 256 + ck * 8 + 4] = c4;
    S8 s; s.w[0] = pk2(a.x, a.y);  s.w[1] = pk2(a.z, a.w);
          s.w[2] = pk2(c4.x, c4.y); s.w[3] = pk2(c4.z, c4.w);
    *(short8*)(xk + (size_t)(b * 1024 + tt * 32 + row) * 256 + ((ck ^ row) << 3)) = s.v;
  }
  __syncthreads();

  // phase 2: transpose from LDS -> staged swizzled V^T tile + colsum partials
  const int ck = tid >> 6, clo = tid & 63;
#pragma unroll
  for (int g = 0; g < 4; ++g) {
    int c = g * 64 + clo;
    float vs[8]; float s = 0.f;
#pragma unroll
    for (int e = 0; e < 8; ++e) { vs[e] = Xt[(ck * 8 + e) * 256 + c]; s += vs[e]; }
    S8 o;
    o.w[0] = pk2(vs[0], vs[1]); o.w[1] = pk2(vs[2], vs[3]);
    o.w[2] = pk2(vs[4], vs[5]); o.w[3] = pk2(vs[6], vs[7]);
    *(short8*)&Vt[c * 32 + (((ck ^ ((c >> 1) & 3)) & 3) << 3)] = o.v;
    csum[ck][c] = s;
  }
  __syncthreads();

  // phase 3: linear coalesced copy-out of V^T tile + colsum reduce
  {
    float4* vo = (float4*)(xv + (size_t)(b * 32 + tt) * 8192);
    const float4* vi = (const float4*)Vt;
#pragma unroll
    for (int r = 0; r < 4; ++r) vo[r * 256 + tid] = vi[r * 256 + tid];
    float s = csum[0][tid] + csum[1][tid] + csum[2][tid] + csum[3][tid];
    atomicAdd(&colsum[b * 256 + tid], s);
  }
}

// ---------------- flash finalize helper ----------------
__device__ __forceinline__ void finalize_tile(
    f32x4* Oa, float m, float l, int b, int quad, int r,
    const float* __restrict__ colsum, const float* __restrict__ gamma,
    const float* __restrict__ beta, float* __restrict__ accum)
{
  float mr[4], li[4];
#pragma unroll
  for (int reg = 0; reg < 4; ++reg) {
    mr[reg] = __shfl(m, quad * 4 + reg, 64);
    float lr = __shfl(l, quad * 4 + reg, 64);
    li[reg] = 1.f / lr;
  }
#pragma unroll
  for (int ct = 0; ct < 16; ++ct) {
    float cs = colsum[b * C_ + ct * 16 + r] * (1.0f / T_);
#pragma unroll
    for (int reg = 0; reg < 4; ++reg)
      Oa[ct][reg] = (mr[reg] < -1.0e9f) ? cs : Oa[ct][reg] * li[reg];
  }
  float ts[16];
#pragma unroll
  for (int ct = 0; ct < 16; ++ct) ts[ct] = 0.f;
#pragma unroll
  for (int reg = 0; reg < 4; ++reg) {
    float s2 = 0.f;
#pragma unroll
    for (int ct = 0; ct < 16; ++ct) s2 += Oa[ct][reg];
    s2 += __shfl_xor(s2, 1, 64); s2 += __shfl_xor(s2, 2, 64);
    s2 += __shfl_xor(s2, 4, 64); s2 += __shfl_xor(s2, 8, 64);
    float mu = s2 * (1.0f / C_);
    float sq = 0.f;
#pragma unroll
    for (int ct = 0; ct < 16; ++ct) { float d = Oa[ct][reg] - mu; sq += d * d; }
    sq += __shfl_xor(sq, 1, 64); sq += __shfl_xor(sq, 2, 64);
    sq += __shfl_xor(sq, 4, 64); sq += __shfl_xor(sq, 8, 64);
    float rstd = rsqrtf(sq * (1.0f / C_) + LN_EPS);
#pragma unroll
    for (int ct = 0; ct < 16; ++ct) {
      int c = ct * 16 + r;
      ts[ct] += gamma[c] * (Oa[ct][reg] - mu) * rstd + beta[c];
    }
  }
#pragma unroll
  for (int ct = 0; ct < 16; ++ct) {
    ts[ct] += __shfl_xor(ts[ct], 16, 64);
    ts[ct] += __shfl_xor(ts[ct], 32, 64);
  }
  if (quad == 0) {
#pragma unroll
    for (int ct = 0; ct < 16; ++ct)
      atomicAdd(&accum[b * C_ + ct * 16 + r], ts[ct]);
  }
}

// ---------------- flash kernel ----------------
// 256 blocks of 512 threads (8 waves), 1 block/CU, 128 KB LDS.
// Block = (batch b, 128-row q-tile pair (t, 7-t)); UNIFORM 18 iterations of
// 64-key tiles: ascending 0..2(t+1)-1 for qt=t, then descending 15-2t..0 for
// qt=7-t (kt = idx < h0len ? idx : 17-idx). All blocks of a batch touch <=2
// tile streams at any instant; XCD clustering (blockIdx&7 hosts batches = x
// mod 8) keeps those streams L2-resident. Wave owns 16 q rows. Double-
// buffered async DMA staging (64 KB/tile), ONE barrier per 64-key tile.
// T13 defer-max (THR=8): skip the O-rescale unless some lane's row-max grew
// by >8; P is then bounded by e^8, harmless in f32/bf16.
__global__ __launch_bounds__(512, 2) void flash5(
    const short* __restrict__ xk,
    const short* __restrict__ xv,
    const float2* __restrict__ sb,
    const float* __restrict__ gamma,
    const float* __restrict__ beta,
    const float* __restrict__ colsum,
    float* __restrict__ accum)
{
  __shared__ __align__(16) short KsD[2][64 * 256];       // 2 x 32 KB  K rows
  __shared__ __align__(16) short VtD[2][2 * 256 * 32];   // 2 x 32 KB  V^T halves

  const int i0 = blockIdx.x;
  const int x8 = i0 & 7;            // XCD id (heuristic: round-robin dispatch)
  const int s  = i0 >> 3;           // 0..31
  const int b  = x8 + 8 * (s & 7);  // batches = x8 (mod 8) cluster on XCD x8
  const int t  = s >> 3;            // 0..3 -> q-tile pair (t, 7-t)

  const int tid  = threadIdx.x;
  const int w    = tid >> 6;        // 0..7
  const int lane = tid & 63;
  const int quad = lane >> 4;
  const int r    = lane & 15;

  const int h0len = 2 * (t + 1);    // ascending tiles for qt=t

  // ---- state for current q-tile
  int qt   = t;
  int n0   = qt * 128 + w * 16;
  int qrow = n0 + r;
  short8 qf[8];
  {
    const short* qp = xk + (size_t)(b * 1024 + qrow) * 256;
#pragma unroll
    for (int ks = 0; ks < 8; ++ks)
      qf[ks] = *(const short8*)(qp + (((ks * 4 + quad) ^ (qrow & 31)) << 3));
  }
  f32x4 Oa[16];
#pragma unroll
  for (int ct = 0; ct < 16; ++ct) Oa[ct] = (f32x4){0.f, 0.f, 0.f, 0.f};
  float m = NEGF, l = 0.f;

  // prefetch tile 0 into buf 0 (64-key tile: 32 KB K + 32 KB V, linear DMA)
  {
    const short* gk = xk + (size_t)(b * 1024) * 256;
    const short* gv = xv + (size_t)(b * 32) * 8192;
#pragma unroll
    for (int u = 0; u < 4; ++u) {
      int seg = w * 4 + u;          // 0..31, 1 KB each
      async16(gk + seg * 512 + lane * 8, &KsD[0][seg * 512]);
      async16(gv + seg * 512 + lane * 8, &VtD[0][seg * 512]);
    }
  }
  __syncthreads();

  for (int idx = 0; idx < 18; ++idx) {
    const int ibuf = idx & 1;
    if (idx < 17) {   // async prefetch tile(idx+1) into other buffer
      const int nt2 = (idx + 1 < h0len) ? (idx + 1) : (17 - (idx + 1));
      const short* gk = xk + (size_t)(b * 1024 + nt2 * 64) * 256;
      const short* gv = xv + (size_t)(b * 32 + nt2 * 2) * 8192;
#pragma unroll
      for (int u = 0; u < 4; ++u) {
        int seg = w * 4 + u;
        async16(gk + seg * 512 + lane * 8, &KsD[1 - ibuf][seg * 512]);
        async16(gv + seg * 512 + lane * 8, &VtD[1 - ibuf][seg * 512]);
      }
    }

    const int kt  = (idx < h0len) ? idx : (17 - idx);
    const int ktb = kt * 64;
    if (ktb <= n0 + 15) {   // wave-uniform causal tile skip
      // ---- scores S^T = K·Q^T  (64 keys = 4 m-tiles)
      float sc[16];
#pragma unroll
      for (int mt = 0; mt < 4; ++mt) {
        f32x4 acc = (f32x4){0.f, 0.f, 0.f, 0.f};
        const int row = mt * 16 + r;
#pragma unroll
        for (int ks = 0; ks < 8; ++ks) {
          short8 af = *(short8*)&KsD[ibuf][row * 256 + (((ks * 4 + quad) ^ (row & 31)) << 3)];
          acc = __builtin_amdgcn_mfma_f32_16x16x32_bf16(af, qf[ks], acc, 0, 0, 0);
        }
        const int j0 = ktb + mt * 16 + quad * 4;
        float4 sA = *(const float4*)(sb + (size_t)b * 1024 + j0);     // s0,b0,s1,b1
        float4 sB = *(const float4*)(sb + (size_t)b * 1024 + j0 + 2); // s2,b2,s3,b3
        sc[mt * 4 + 0] = acc[0] * sA.x + sA.y;
        sc[mt * 4 + 1] = acc[1] * sA.z + sA.w;
        sc[mt * 4 + 2] = acc[2] * sB.x + sB.y;
        sc[mt * 4 + 3] = acc[3] * sB.z + sB.w;
      }
      if (ktb + 63 > n0) {   // diagonal tiles: elementwise causal mask
#pragma unroll
        for (int k2 = 0; k2 < 16; ++k2) {
          int j = ktb + (k2 >> 2) * 16 + quad * 4 + (k2 & 3);
          if (j > qrow) sc[k2] = NEGF;
        }
      }

      // ---- online softmax (stats per q at lane&15, replicated via xor16/32)
      float mx = sc[0];
#pragma unroll
      for (int k2 = 1; k2 < 16; ++k2) mx = fmaxf(mx, sc[k2]);
      mx = fmaxf(mx, __shfl_xor(mx, 16, 64));
      mx = fmaxf(mx, __shfl_xor(mx, 32, 64));
      if (__ballot(mx > m + 8.f)) {   // T13 defer-max: rescale only on real growth
        const float mnew  = fmaxf(m, mx);
        const float alpha = __expf(m - mnew);   // NEGF-NEGF=0 -> 1; NEGF-real -> 0
        float ar[4];
#pragma unroll
        for (int reg = 0; reg < 4; ++reg) ar[reg] = __shfl(alpha, quad * 4 + reg, 64);
#pragma unroll
        for (int ct = 0; ct < 16; ++ct) {
          Oa[ct][0] *= ar[0]; Oa[ct][1] *= ar[1];
          Oa[ct][2] *= ar[2]; Oa[ct][3] *= ar[3];
        }
        l *= alpha;
        m = mnew;
      }
      float p[16], ps = 0.f;
#pragma unroll
      for (int k2 = 0; k2 < 16; ++k2) { p[k2] = __expf(sc[k2] - m); ps += p[k2]; }
      ps += __shfl_xor(ps, 16, 64);
      ps += __shfl_xor(ps, 32, 64);
      l += ps;

      // ---- P (C-layout) -> two PV A-frags via 8 shuffles each
      S8 pf[2];
#pragma unroll
      for (int hh = 0; hh < 2; ++hh) {
        unsigned q0 = pk2(p[hh * 8 + 0], p[hh * 8 + 1]);
        unsigned q1 = pk2(p[hh * 8 + 2], p[hh * 8 + 3]);
        unsigned q2 = pk2(p[hh * 8 + 4], p[hh * 8 + 5]);
        unsigned q3 = pk2(p[hh * 8 + 6], p[hh * 8 + 7]);
        int s0l = ((quad & 1) << 5) + r, s1l = s0l + 16;
        unsigned u0 = __shfl((int)q0, s0l, 64), u1 = __shfl((int)q1, s0l, 64);
        unsigned u2 = __shfl((int)q2, s0l, 64), u3 = __shfl((int)q3, s0l, 64);
        unsigned v0 = __shfl((int)q0, s1l, 64), v1 = __shfl((int)q1, s1l, 64);
        unsigned v2 = __shfl((int)q2, s1l, 64), v3 = __shfl((int)q3, s1l, 64);
        bool hi = quad >= 2;
        pf[hh].w[0] = hi ? u2 : u0; pf[hh].w[1] = hi ? u3 : u1;
        pf[hh].w[2] = hi ? v2 : v0; pf[hh].w[3] = hi ? v3 : v1;
      }

      // ---- PV: O[q][c] += P[q][j] V[j][c]  (two 32-key halves)
#pragma unroll
      for (int ct = 0; ct < 16; ++ct) {
        int c = ct * 16 + r;
        int cs_off = c * 32 + (((quad ^ ((c >> 1) & 3)) & 3) << 3);
        short8 b0 = *(short8*)&VtD[ibuf][cs_off];
        short8 b1 = *(short8*)&VtD[ibuf][8192 + cs_off];
        Oa[ct] = __builtin_amdgcn_mfma_f32_16x16x32_bf16(pf[0].v, b0, Oa[ct], 0, 0, 0);
        Oa[ct] = __builtin_amdgcn_mfma_f32_16x16x32_bf16(pf[1].v, b1, Oa[ct], 0, 0, 0);
      }
    }

    // ---- boundary: finalize qt=t, reset state for qt=7-t (no LDS touched)
    if (idx == h0len - 1) {
      finalize_tile(Oa, m, l, b, quad, r, colsum, gamma, beta, accum);
      qt = 7 - t;
      n0 = qt * 128 + w * 16;
      qrow = n0 + r;
      const short* qp = xk + (size_t)(b * 1024 + qrow) * 256;
#pragma unroll
      for (int ks = 0; ks < 8; ++ks)
        qf[ks] = *(const short8*)(qp + (((ks * 4 + quad) ^ (qrow & 31)) << 3));
#pragma unroll
      for (int ct = 0; ct < 16; ++ct) Oa[ct] = (f32x4){0.f, 0.f, 0.f, 0.f};
      m = NEGF; l = 0.f;
    }

    __syncthreads();   // drains prefetched tile(idx+1) (issued a full tile ago)
  } // idx

  // ---- finalize second q-tile (qt = 7-t)
  finalize_tile(Oa, m, l, b, quad, r, colsum, gamma, beta, accum);
}

// ---------------- launch ----------------

extern "C" void kernel_launch(void* const* d_in, const int* in_sizes, int n_in,
                              void* d_out, int out_size, void* d_ws, size_t ws_size,
                              hipStream_t stream) {
  const float* x     = (const float*)d_in[0];
  const void*  km    = d_in[1];
  const float* gamma = (const float*)d_in[2];
  const float* beta  = (const float*)d_in[3];
  float* out = (float*)d_out;

  // ws layout
  const size_t off_sb = 131200;                       // float2[B*T] = 512 KB
  const size_t off_xk = 655616;                       // 32 MB bf16 K-image
  const size_t off_xv = off_xk + 33554432;            // 32 MB bf16 V^T-image

  float*  accum  = (float*)d_ws;
  float*  colsum = (float*)((char*)d_ws + 65536);
  int*    flag   = (int*)((char*)d_ws + 131072);
  float2* sb     = (float2*)((char*)d_ws + off_sb);
  short*  xk     = (short*)((char*)d_ws + off_xk);
  short*  xv     = (short*)((char*)d_ws + off_xv);

  hipMemsetAsync(d_ws, 0, 131136, stream);   // accum + colsum + flag
  detect_kernel<<<64, 256, 0, stream>>>((const unsigned int*)km, flag);
  convert_kv<<<B_ * 32, 256, 0, stream>>>(x, (const unsigned int*)km, flag,
                                          xk, xv, colsum, sb);
  flash5<<<256, 512, 0, stream>>>(xk, xv, sb, gamma, beta, colsum, accum);
  finalize_kernel<<<B_ * C_ / 256, 256, 0, stream>>>(accum, out);
}